// Round 4
// baseline (4545.620 us; speedup 1.0000x reference)
//
#include <hip/hip_runtime.h>

#define T_SEQ 512
#define HID 256

typedef _Float16 half8 __attribute__((ext_vector_type(8)));
typedef _Float16 half4 __attribute__((ext_vector_type(4)));
typedef float floatx4 __attribute__((ext_vector_type(4)));

// ws layout (f16 elements): gh frags | gi frags | w_base frags | w_dir/mag frags
#define OFF_GH 0
#define OFF_GI (OFF_GH + 384 * 512)
#define OFF_WB (OFF_GI + 96 * 512)
#define OFF_WD (OFF_WB + 128 * 512)

#define MFMA16(A, B, C) __builtin_amdgcn_mfma_f32_16x16x32_f16(A, B, C, 0, 0, 0)

__device__ __forceinline__ float sigm(float x) { return 1.0f / (1.0f + __expf(-x)); }
__device__ __forceinline__ float tanh_fast(float x) {
  float e = __expf(2.0f * x);
  return 1.0f - 2.0f / (e + 1.0f);
}

// Pack all weights (fp32 in) into f16 MFMA B-fragment order.
__global__ void prep_kernel(const float* __restrict__ w_ih,
                            const float* __restrict__ w_hh,
                            const float* __restrict__ w_base,
                            const float* __restrict__ w_dir,
                            const float* __restrict__ w_mag,
                            _Float16* __restrict__ ws) {
  const int f = blockIdx.x;
  const int lane = threadIdx.x;
  const int col = lane & 15, quad = lane >> 4;
  const float* src;
  int n, k, ld;
  _Float16* dst;
  if (f < 384) {  // w_hh frags: f = (w*8 + kt)*6 + nt ; nt: 0,1=r 2,3=z 4,5=n
    int nt = f % 6, kt = (f / 6) % 8, w = f / 48;
    n = (nt >> 1) * 256 + w * 32 + (nt & 1) * 16 + col;
    k = kt * 32 + quad * 8;
    src = w_hh; ld = 256;
    dst = ws + OFF_GH + ((w * 8 + kt) * 6 + nt) * 512 + lane * 8;
  } else if (f < 480) {  // w_ih frags: f2 = (w*2 + kt)*6 + nt
    int f2 = f - 384;
    int nt = f2 % 6, kt = (f2 / 6) % 2, w = f2 / 12;
    n = (nt >> 1) * 256 + w * 32 + (nt & 1) * 16 + col;
    k = kt * 32 + quad * 8;
    src = w_ih; ld = 64;
    dst = ws + OFF_GI + ((w * 2 + kt) * 6 + nt) * 512 + lane * 8;
  } else if (f < 608) {  // w_base frags
    int f3 = f - 480;
    int nt = f3 % 2, kt = (f3 / 2) % 8, w = f3 / 16;
    n = w * 32 + nt * 16 + col;
    k = kt * 32 + quad * 8;
    src = w_base; ld = 256;
    dst = ws + OFF_WB + ((w * 8 + kt) * 2 + nt) * 512 + lane * 8;
  } else {  // dir/mag combined: cols 0..7 dir, 8..15 mag
    int kt = f - 608;
    k = kt * 32 + quad * 8;
    ld = 256;
    if (col < 8) { src = w_dir; n = col; } else { src = w_mag; n = col - 8; }
    dst = ws + OFF_WD + kt * 512 + lane * 8;
  }
#pragma unroll
  for (int j = 0; j < 8; ++j)
    dst[j] = (_Float16)src[n * ld + k + j];
}

// One GRU step. XCUR/XNEXT are the NAMES of float4[4] arrays (token-pasted,
// all indices compile-time => registers). Order: st loads first (oldest in
// vmcnt, so their wait never drains the x prefetch), then x prefetch for t+1
// (consumed one full body later => zero exposed latency), cvt of current x
// (already resident), gi MFMAs (register-only, cover the ah lgkm latency),
// 40 resident MFMAs, 8 streamed MFMAs.
#define GRU_BODY(XCUR, XNEXT, TPRE, CUR)                                       \
  {                                                                            \
    __syncthreads();                                                           \
    const _Float16* hc = hlin[CUR];                                            \
    _Float16* hn = hlin[(CUR) ^ 1];                                            \
    half8 st[8];                                                               \
    _Pragma("unroll")                                                          \
    for (int i = 0; i < 8; ++i) st[i] = ghp[(40 + i) * 64 + lane];             \
    {                                                                          \
      const float* p = xlane + (size_t)(TPRE) * 64;                            \
      XNEXT[0] = *(const float4*)(p);                                          \
      XNEXT[1] = *(const float4*)(p + 4);                                      \
      XNEXT[2] = *(const float4*)(p + 32);                                     \
      XNEXT[3] = *(const float4*)(p + 36);                                     \
    }                                                                          \
    half8 ax0, ax1;                                                            \
    ax0[0] = (_Float16)XCUR[0].x; ax0[1] = (_Float16)XCUR[0].y;                \
    ax0[2] = (_Float16)XCUR[0].z; ax0[3] = (_Float16)XCUR[0].w;                \
    ax0[4] = (_Float16)XCUR[1].x; ax0[5] = (_Float16)XCUR[1].y;                \
    ax0[6] = (_Float16)XCUR[1].z; ax0[7] = (_Float16)XCUR[1].w;                \
    ax1[0] = (_Float16)XCUR[2].x; ax1[1] = (_Float16)XCUR[2].y;                \
    ax1[2] = (_Float16)XCUR[2].z; ax1[3] = (_Float16)XCUR[2].w;                \
    ax1[4] = (_Float16)XCUR[3].x; ax1[5] = (_Float16)XCUR[3].y;                \
    ax1[6] = (_Float16)XCUR[3].z; ax1[7] = (_Float16)XCUR[3].w;                \
    half8 ah[8];                                                               \
    _Pragma("unroll")                                                          \
    for (int kt = 0; kt < 8; ++kt)                                             \
      ah[kt] = *(const half8*)&hc[kt * 512 + lane * 8];                        \
    floatx4 acc[8];                                                            \
    _Pragma("unroll")                                                          \
    for (int i = 0; i < 8; ++i) acc[i] = (floatx4){0.f, 0.f, 0.f, 0.f};        \
    __builtin_amdgcn_s_setprio(1);                                             \
    _Pragma("unroll")                                                          \
    for (int nt = 0; nt < 6; ++nt) {                                           \
      const int aidx = (nt < 4) ? nt : nt + 2;                                 \
      acc[aidx] = MFMA16(ax0, wg[nt], acc[aidx]);                              \
      acc[aidx] = MFMA16(ax1, wg[6 + nt], acc[aidx]);                          \
    }                                                                          \
    _Pragma("unroll")                                                          \
    for (int f = 0; f < 40; ++f)                                               \
      acc[f % 6] = MFMA16(ah[f / 6], wreg[f], acc[f % 6]);                     \
    _Pragma("unroll")                                                          \
    for (int i = 0; i < 8; ++i) {                                              \
      const int f = 40 + i;                                                    \
      acc[f % 6] = MFMA16(ah[f / 6], st[i], acc[f % 6]);                       \
    }                                                                          \
    __builtin_amdgcn_s_setprio(0);                                             \
    _Pragma("unroll")                                                          \
    for (int s = 0; s < 2; ++s) {                                              \
      const int inner = s * 16 + col;                                          \
      const int widx = w * 512 + (inner >> 3) * 128 + (col & 7);               \
      _Pragma("unroll")                                                        \
      for (int r2 = 0; r2 < 4; ++r2) {                                         \
        const float rr = sigm(acc[0 + s][r2] + br[s]);                         \
        const float zz = sigm(acc[2 + s][r2] + bz[s]);                         \
        const float nn = tanh_fast(acc[6 + s][r2] + bin_[s] +                  \
                                   rr * (acc[4 + s][r2] + bhn[s]));            \
        const float hnew = zz * hreg[s][r2] + (1.0f - zz) * nn;                \
        hreg[s][r2] = hnew;                                                    \
        hn[widx + (quad * 4 + r2) * 8] = (_Float16)hnew;                       \
      }                                                                        \
    }                                                                          \
  }

// Single self-contained sequential kernel: 64 blocks (16 batch rows each) x
// 512 threads, 1 block/CU. Per step: 60 MFMAs — 40 AGPR-resident gh frags,
// 12 AGPR-resident gi (w_ih) frags fed by x prefetched one step ahead,
// 8 gh frags streamed from L2.
// R4 fix: the 52 persistent weight frags are PINNED to AGPRs via empty
// inline-asm "+a" constraints (gfx950 MFMA reads B directly from AGPR).
// R2/R3 showed the allocator spilling exactly this set to scratch instead
// (WRITE_SIZE 32 MB = ~832B/thread one-time + per-step reloads, 2.7x slow).
// Budget: AGPR = 52*4 + acc 32 = 240 <= 256 ; VGPR ~= 120 <= 128.
__global__ __launch_bounds__(512, 1)
void gru_all_kernel(const float* __restrict__ x_seq,
                    const float* __restrict__ b_ih,
                    const float* __restrict__ b_hh,
                    const float* __restrict__ b_base,
                    const float* __restrict__ b_dir,
                    const float* __restrict__ b_mag,
                    const _Float16* __restrict__ ws,
                    float* __restrict__ out) {
  __shared__ __align__(16) _Float16 hlin[2][4096];  // [kt(8)][q(4)][row(16)][8]

  const int tid = threadIdx.x;
  const int lane = tid & 63;
  const int w = tid >> 6;
  const int col = lane & 15;
  const int quad = lane >> 4;
  const int row0 = blockIdx.x * 16;

  float br[2], bz[2], bin_[2], bhn[2];
#pragma unroll
  for (int s = 0; s < 2; ++s) {
    const int c = w * 32 + s * 16 + col;
    br[s] = b_ih[c] + b_hh[c];
    bz[s] = b_ih[256 + c] + b_hh[256 + c];
    bin_[s] = b_ih[512 + c];
    bhn[s] = b_hh[512 + c];
  }

  float hreg[2][4];
#pragma unroll
  for (int s = 0; s < 2; ++s)
#pragma unroll
    for (int r2 = 0; r2 < 4; ++r2) hreg[s][r2] = 0.0f;
  *(half8*)&hlin[0][tid * 8] = (half8)((_Float16)0.0f);

  const half8* __restrict__ ghp = (const half8*)(ws + OFF_GH) + w * (48 * 64);
  const half8* __restrict__ gip = (const half8*)(ws + OFF_GI) + w * (12 * 64);
  const half8* __restrict__ wbp = (const half8*)(ws + OFF_WB) + w * (16 * 64);
  const half8* __restrict__ wdp = (const half8*)(ws + OFF_WD);

  // persistent weights: 40 gh frags + 12 gi frags, PINNED to AGPRs
  half8 wreg[40];
#pragma unroll
  for (int f = 0; f < 40; ++f) wreg[f] = ghp[f * 64 + lane];
  half8 wg[12];
#pragma unroll
  for (int f = 0; f < 12; ++f) wg[f] = gip[f * 64 + lane];
#pragma unroll
  for (int f = 0; f < 40; ++f) asm volatile("" : "+a"(wreg[f]));
#pragma unroll
  for (int f = 0; f < 12; ++f) asm volatile("" : "+a"(wg[f]));

  const float* const xlane =
      x_seq + (size_t)(row0 + col) * (T_SEQ * 64) + quad * 8;
  float4 xc[4], xn[4];
  {
    const float* p = xlane;  // t = 0
    xc[0] = *(const float4*)(p);
    xc[1] = *(const float4*)(p + 4);
    xc[2] = *(const float4*)(p + 32);
    xc[3] = *(const float4*)(p + 36);
  }

#pragma unroll 1
  for (int t = 0; t < T_SEQ; t += 2) {
    GRU_BODY(xc, xn, t + 1, 0);
    const int tp2 = (t + 2 < T_SEQ) ? (t + 2) : (T_SEQ - 1);
    GRU_BODY(xn, xc, tp2, 1);
  }

  __syncthreads();
  // head: base = relu(hT @ w_base^T + b_base); h_T in hlin[0] (T even)
  {
    floatx4 ab[2];
    ab[0] = (floatx4){0.f, 0.f, 0.f, 0.f};
    ab[1] = (floatx4){0.f, 0.f, 0.f, 0.f};
#pragma unroll
    for (int kt = 0; kt < 8; ++kt) {
      const half8 ahh = *(const half8*)&hlin[0][kt * 512 + lane * 8];
      const half8* bp = wbp + kt * (2 * 64) + lane;
      ab[0] = MFMA16(ahh, bp[0],  ab[0]);
      ab[1] = MFMA16(ahh, bp[64], ab[1]);
    }
#pragma unroll
    for (int s = 0; s < 2; ++s) {
      const int inner = s * 16 + col;
      const int widx = w * 512 + (inner >> 3) * 128 + (col & 7);
      const float bb = b_base[w * 32 + inner];
#pragma unroll
      for (int r2 = 0; r2 < 4; ++r2) {
        const float v = ab[s][r2] + bb;
        hlin[1][widx + (quad * 4 + r2) * 8] = (_Float16)fmaxf(v, 0.0f);
      }
    }
  }
  __syncthreads();

  if (w == 0) {
    floatx4 ad = (floatx4){0.f, 0.f, 0.f, 0.f};
#pragma unroll
    for (int kt = 0; kt < 8; ++kt) {
      const half8 ahh = *(const half8*)&hlin[1][kt * 512 + lane * 8];
      ad = MFMA16(ahh, wdp[kt * 64 + lane], ad);
    }
    const float bd = (col < 8) ? b_dir[col] : b_mag[col - 8];
#pragma unroll
    for (int r2 = 0; r2 < 4; ++r2) {
      const float v = ad[r2] + bd;
      const float act = (col < 8) ? tanh_fast(v) : sigm(v);
      const float other = __shfl_xor(act, 8, 64);
      if (col < 8)
        out[(size_t)(row0 + quad * 4 + r2) * 8 + col] = act * other;
    }
  }
}

extern "C" void kernel_launch(void* const* d_in, const int* in_sizes, int n_in,
                              void* d_out, int out_size, void* d_ws, size_t ws_size,
                              hipStream_t stream) {
  const float* x_seq  = (const float*)d_in[0];
  const float* b_ih   = (const float*)d_in[3];
  const float* b_hh   = (const float*)d_in[4];
  const float* b_base = (const float*)d_in[6];
  const float* b_dir  = (const float*)d_in[8];
  const float* b_mag  = (const float*)d_in[10];
  _Float16* ws = (_Float16*)d_ws;
  float* out = (float*)d_out;

  hipLaunchKernelGGL(prep_kernel, dim3(616), dim3(64), 0, stream,
                     (const float*)d_in[1], (const float*)d_in[2],
                     (const float*)d_in[5], (const float*)d_in[7],
                     (const float*)d_in[9], ws);

  hipLaunchKernelGGL(gru_all_kernel, dim3(64), dim3(512), 0, stream,
                     x_seq, b_ih, b_hh, b_base, b_dir, b_mag, ws, out);
}

// Round 6
// 4000.590 us; speedup vs baseline: 1.1362x; 1.1362x over previous
//
#include <hip/hip_runtime.h>

#define T_SEQ 512
#define HID 256

typedef _Float16 half8 __attribute__((ext_vector_type(8)));
typedef _Float16 half4 __attribute__((ext_vector_type(4)));
typedef float floatx4 __attribute__((ext_vector_type(4)));

// ws layout (f16 element offsets for weight frags):
//   old layout (fallback kernel):  gh | gi | wb | wd
//   new layout (split kernel):     gh2 (per q,w) | gi2 (per q,w)
// byte offsets: seq flags @2MB, hx exchange @3MB, x16 @8MB (64MB)
#define OFF_GH 0
#define OFF_GI (OFF_GH + 384 * 512)
#define OFF_WB (OFF_GI + 96 * 512)
#define OFF_WD (OFF_WB + 128 * 512)
#define OFF_GH2 (OFF_WD + 16 * 512)
#define OFF_GI2 (OFF_GH2 + 384 * 512)
#define SEQ_OFF_BYTES (2ull << 20)
#define HX_OFF_BYTES (3ull << 20)
#define X16_OFF_BYTES (8ull << 20)
#define WS_NEED_BYTES (80ull << 20)

#define MFMA16(A, B, C) __builtin_amdgcn_mfma_f32_16x16x32_f16(A, B, C, 0, 0, 0)

__device__ __forceinline__ float sigm(float x) { return 1.0f / (1.0f + __expf(-x)); }
__device__ __forceinline__ float tanh_fast(float x) {
  float e = __expf(2.0f * x);
  return 1.0f - 2.0f / (e + 1.0f);
}

// Pack all weights (fp32 in) into f16 MFMA B-fragment order (both layouts) +
// zero the exchange flags.
__global__ void prep_kernel(const float* __restrict__ w_ih,
                            const float* __restrict__ w_hh,
                            const float* __restrict__ w_base,
                            const float* __restrict__ w_dir,
                            const float* __restrict__ w_mag,
                            _Float16* __restrict__ ws) {
  const int f = blockIdx.x;
  const int lane = threadIdx.x;
  const int col = lane & 15, quad = lane >> 4;
  const float* src;
  int n, k, ld;
  _Float16* dst;
  if (f < 384) {  // old w_hh frags: f = (w*8 + kt)*6 + nt
    int nt = f % 6, kt = (f / 6) % 8, w = f / 48;
    n = (nt >> 1) * 256 + w * 32 + (nt & 1) * 16 + col;
    k = kt * 32 + quad * 8;
    src = w_hh; ld = 256;
    dst = ws + OFF_GH + ((w * 8 + kt) * 6 + nt) * 512 + lane * 8;
  } else if (f < 480) {  // old w_ih frags
    int f2 = f - 384;
    int nt = f2 % 6, kt = (f2 / 6) % 2, w = f2 / 12;
    n = (nt >> 1) * 256 + w * 32 + (nt & 1) * 16 + col;
    k = kt * 32 + quad * 8;
    src = w_ih; ld = 64;
    dst = ws + OFF_GI + ((w * 2 + kt) * 6 + nt) * 512 + lane * 8;
  } else if (f < 608) {  // w_base frags
    int f3 = f - 480;
    int nt = f3 % 2, kt = (f3 / 2) % 8, w = f3 / 16;
    n = w * 32 + nt * 16 + col;
    k = kt * 32 + quad * 8;
    src = w_base; ld = 256;
    dst = ws + OFF_WB + ((w * 8 + kt) * 2 + nt) * 512 + lane * 8;
  } else if (f < 616) {  // dir/mag combined
    int kt = f - 608;
    k = kt * 32 + quad * 8;
    ld = 256;
    if (col < 8) { src = w_dir; n = col; } else { src = w_mag; n = col - 8; }
    dst = ws + OFF_WD + kt * 512 + lane * 8;
  } else if (f < 1000) {  // gh2 frags: per (qw = q*4+w): [kt(8)][g(3)]
    int f2 = f - 616;
    int g = f2 % 3, kt = (f2 / 3) % 8, qw = f2 / 24;
    n = g * 256 + qw * 16 + col;
    k = kt * 32 + quad * 8;
    src = w_hh; ld = 256;
    dst = ws + OFF_GH2 + ((qw * 8 + kt) * 3 + g) * 512 + lane * 8;
  } else if (f < 1096) {  // gi2 frags: per qw: [kt2(2)][g(3)]
    int f3 = f - 1000;
    int g = f3 % 3, kt = (f3 / 3) % 2, qw = f3 / 6;
    n = g * 256 + qw * 16 + col;
    k = kt * 32 + quad * 8;
    src = w_ih; ld = 64;
    dst = ws + OFF_GI2 + ((qw * 2 + kt) * 3 + g) * 512 + lane * 8;
  } else {  // f == 1096: zero the 256 exchange flags
    unsigned* sq = (unsigned*)((char*)ws + SEQ_OFF_BYTES);
#pragma unroll
    for (int i = 0; i < 4; ++i) sq[lane * 4 + i] = 0u;
    return;
  }
#pragma unroll
  for (int j = 0; j < 8; ++j)
    dst[j] = (_Float16)src[n * ld + k + j];
}

// Convert x_seq fp32 -> f16 (same layout) once per call.
__global__ __launch_bounds__(256)
void x16_kernel(const float* __restrict__ x, _Float16* __restrict__ x16) {
  const size_t N8 = (size_t)1024 * 512 * 64 / 8;
  const size_t stride = (size_t)gridDim.x * blockDim.x;
  for (size_t i = (size_t)blockIdx.x * blockDim.x + threadIdx.x; i < N8; i += stride) {
    const float4 a = *(const float4*)(x + i * 8);
    const float4 b = *(const float4*)(x + i * 8 + 4);
    half8 h;
    h[0] = (_Float16)a.x; h[1] = (_Float16)a.y; h[2] = (_Float16)a.z; h[3] = (_Float16)a.w;
    h[4] = (_Float16)b.x; h[5] = (_Float16)b.y; h[6] = (_Float16)b.z; h[7] = (_Float16)b.w;
    *(half8*)(x16 + i * 8) = h;
  }
}

// One exchange-GRU step for block (rg, q), wave w owning 16 hidden units.
// AXC/AXN are NAMES of half8[2] arrays (static indices -> registers).
// Protocol: [spin sib flags >= t] -> [agent sc1 loads of h_t A-frags from LLC]
// -> gi MFMAs (cover load latency) -> x prefetch (t+1) -> gh MFMAs -> epilogue
// -> LDS transpose to A-frag layout -> agent sc1 stores -> vmcnt(0) -> barrier
// -> flag := t+1 (RELEASE). Parity double-buffer; WAR-safe: writing slot
// (t+1)&1 requires flags >= t, which implies siblings finished reading slot
// (t-1)&1. Element-level layout verified by hand (R5 post-mortem).
#define STEP(AXC, AXN, T)                                                      \
  {                                                                            \
    const int t_ = (T);                                                        \
    if (t_ > 0) {                                                              \
      if (tid < 3) {                                                           \
        const int sib = rg4 + ((q + 1 + tid) & 3);                             \
        unsigned gd = 0;                                                       \
        while (__hip_atomic_load(&seqp[sib], __ATOMIC_RELAXED,                 \
                                 __HIP_MEMORY_SCOPE_AGENT) < (unsigned)t_) {   \
          if (++gd > (1u << 24)) break;                                        \
        }                                                                      \
      }                                                                        \
      __syncthreads();                                                         \
    }                                                                          \
    half8 ah[8];                                                               \
    if (t_ > 0) {                                                              \
      const unsigned long long* hp =                                           \
          hxp + (size_t)((t_ & 1) * 64 + rg) * 1024 + lane * 2;                \
      _Pragma("unroll")                                                        \
      for (int i = 0; i < 8; ++i) {                                            \
        union { unsigned long long u[2]; half8 h; } cv;                        \
        cv.u[0] = __hip_atomic_load(hp + i * 128, __ATOMIC_RELAXED,            \
                                    __HIP_MEMORY_SCOPE_AGENT);                 \
        cv.u[1] = __hip_atomic_load(hp + i * 128 + 1, __ATOMIC_RELAXED,        \
                                    __HIP_MEMORY_SCOPE_AGENT);                 \
        ah[i] = cv.h;                                                          \
      }                                                                        \
    }                                                                          \
    floatx4 aR = {0.f, 0.f, 0.f, 0.f}, aZ = {0.f, 0.f, 0.f, 0.f};             \
    floatx4 aNH = {0.f, 0.f, 0.f, 0.f}, aNX = {0.f, 0.f, 0.f, 0.f};           \
    _Pragma("unroll")                                                          \
    for (int k2 = 0; k2 < 2; ++k2) {                                           \
      aR = MFMA16(AXC[k2], wgi[k2 * 3 + 0], aR);                               \
      aZ = MFMA16(AXC[k2], wgi[k2 * 3 + 1], aZ);                               \
      aNX = MFMA16(AXC[k2], wgi[k2 * 3 + 2], aNX);                             \
    }                                                                          \
    {                                                                          \
      const int tn = (t_ + 1 < T_SEQ) ? t_ + 1 : t_;                           \
      AXN[0] = *(const half8*)(xlane16 + (size_t)tn * 64);                     \
      AXN[1] = *(const half8*)(xlane16 + (size_t)tn * 64 + 32);                \
    }                                                                          \
    if (t_ > 0) {                                                              \
      _Pragma("unroll")                                                        \
      for (int kt = 0; kt < 8; ++kt) {                                         \
        aR = MFMA16(ah[kt], wgh[kt * 3 + 0], aR);                              \
        aZ = MFMA16(ah[kt], wgh[kt * 3 + 1], aZ);                              \
        aNH = MFMA16(ah[kt], wgh[kt * 3 + 2], aNH);                            \
      }                                                                        \
    }                                                                          \
    _Pragma("unroll")                                                          \
    for (int r2 = 0; r2 < 4; ++r2) {                                           \
      const float rr = sigm(aR[r2] + br);                                      \
      const float zz = sigm(aZ[r2] + bz);                                      \
      const float nn = tanh_fast(aNX[r2] + bin_ + rr * (aNH[r2] + bhn));       \
      const float hnew = zz * hreg[r2] + (1.0f - zz) * nn;                     \
      hreg[r2] = hnew;                                                         \
      hq[hqw + r2 * 8] = (_Float16)hnew;                                       \
    }                                                                          \
    __syncthreads();                                                           \
    if (tid < 128) {                                                           \
      const int kt = tid >> 6, l = tid & 63;                                   \
      union { uint4 u4; unsigned long long u[2]; } cv;                         \
      cv.u4 = *(const uint4*)&hq[kt * 512 + l * 8];                            \
      unsigned long long* dp = hxp +                                           \
          (size_t)(((t_ + 1) & 1) * 64 + rg) * 1024 + (q * 2 + kt) * 128 + l * 2; \
      __hip_atomic_store(dp, cv.u[0], __ATOMIC_RELAXED,                        \
                         __HIP_MEMORY_SCOPE_AGENT);                            \
      __hip_atomic_store(dp + 1, cv.u[1], __ATOMIC_RELAXED,                    \
                         __HIP_MEMORY_SCOPE_AGENT);                            \
      asm volatile("s_waitcnt vmcnt(0)" ::: "memory");                         \
    }                                                                          \
    __syncthreads();                                                           \
    if (tid == 0)                                                              \
      __hip_atomic_store(&seqp[rg4 + q], (unsigned)(t_ + 1),                   \
                         __ATOMIC_RELEASE, __HIP_MEMORY_SCOPE_AGENT);          \
  }

// Hidden-split kernel: 256 blocks (64 row-groups x 4 unit-quarters) x 256 thr.
// All weight frags register-resident (30 frags/wave = 120 regs; 1 wave/SIMD
// => 512-reg budget). Zero per-step weight traffic — the 480KB/CU/step L2
// streaming that capped every previous kernel at ~7300 cyc/step is gone.
// PLAIN launch (R6): cooperative launch is not graph-capture-safe (R5 failed
// with out never written). Co-residency is structural: 1 block/CU, grid=256.
__global__ __launch_bounds__(256, 1)
void gru_coop_kernel(const _Float16* __restrict__ x16,
                     const float* __restrict__ b_ih,
                     const float* __restrict__ b_hh,
                     const float* __restrict__ b_base,
                     const float* __restrict__ b_dir,
                     const float* __restrict__ b_mag,
                     const _Float16* __restrict__ ws,
                     unsigned* __restrict__ seqp,
                     unsigned long long* __restrict__ hxp,
                     float* __restrict__ out) {
  __shared__ __align__(16) _Float16 hq[1024];   // per-step quarter transpose
  __shared__ __align__(16) _Float16 hl2[4096];  // head: base activations

  const int tid = threadIdx.x;
  const int lane = tid & 63;
  const int w = tid >> 6;       // 4 waves
  const int col = lane & 15;
  const int quad = lane >> 4;
  const int rg = blockIdx.x >> 2;
  const int q = blockIdx.x & 3;
  const int rg4 = rg * 4;
  const int row0 = rg * 16;

  // this wave owns hidden units [q*64 + w*16, +16)
  const int c = q * 64 + w * 16 + col;
  const float br = b_ih[c] + b_hh[c];
  const float bz = b_ih[256 + c] + b_hh[256 + c];
  const float bin_ = b_ih[512 + c];
  const float bhn = b_hh[512 + c];

  // register-resident weight frags
  const int qw = q * 4 + w;
  const half8* __restrict__ gh2 = (const half8*)(ws + OFF_GH2) + qw * (24 * 64);
  const half8* __restrict__ gi2 = (const half8*)(ws + OFF_GI2) + qw * (6 * 64);
  half8 wgh[24];
#pragma unroll
  for (int f = 0; f < 24; ++f) wgh[f] = gh2[f * 64 + lane];
  half8 wgi[6];
#pragma unroll
  for (int f = 0; f < 6; ++f) wgi[f] = gi2[f * 64 + lane];

  // LDS transpose address for this thread's 4 h values (unit, row=quad*4+r2)
  const int ul = w * 16 + col;  // unit_local 0..63
  const int hqw = (ul >> 5) * 512 + (((ul >> 3) & 3) * 16 + quad * 4) * 8 + (ul & 7);

  float hreg[4];
#pragma unroll
  for (int r2 = 0; r2 < 4; ++r2) hreg[r2] = 0.0f;

  const _Float16* const xlane16 =
      x16 + (size_t)(row0 + col) * (T_SEQ * 64) + quad * 8;
  half8 axc[2], axn[2];
  axc[0] = *(const half8*)(xlane16);
  axc[1] = *(const half8*)(xlane16 + 32);

#pragma unroll 1
  for (int t = 0; t < T_SEQ; t += 2) {
    STEP(axc, axn, t);
    STEP(axn, axc, t + 1);
  }

  // ---- head (blocks with q == 0 only; h_512 in slot parity 0) ----
  if (q != 0) return;
  if (tid < 3) {
    const int sib = rg4 + 1 + tid;
    unsigned gd = 0;
    while (__hip_atomic_load(&seqp[sib], __ATOMIC_RELAXED,
                             __HIP_MEMORY_SCOPE_AGENT) < (unsigned)T_SEQ) {
      if (++gd > (1u << 24)) break;
    }
  }
  __syncthreads();

  half8 ah[8];
  {
    const unsigned long long* hp = hxp + (size_t)rg * 1024 + lane * 2;  // parity 0
#pragma unroll
    for (int i = 0; i < 8; ++i) {
      union { unsigned long long u[2]; half8 h; } cv;
      cv.u[0] = __hip_atomic_load(hp + i * 128, __ATOMIC_RELAXED,
                                  __HIP_MEMORY_SCOPE_AGENT);
      cv.u[1] = __hip_atomic_load(hp + i * 128 + 1, __ATOMIC_RELAXED,
                                  __HIP_MEMORY_SCOPE_AGENT);
      ah[i] = cv.h;
    }
  }

  // base = relu(h @ w_base^T + b_base); wave w owns units [w*64, w*64+64)
  {
    const half8* __restrict__ wbp = (const half8*)(ws + OFF_WB);
    floatx4 ab[4];
#pragma unroll
    for (int nt = 0; nt < 4; ++nt) ab[nt] = (floatx4){0.f, 0.f, 0.f, 0.f};
#pragma unroll
    for (int kt = 0; kt < 8; ++kt) {
#pragma unroll
      for (int nt = 0; nt < 4; ++nt) {
        const int fragid = ((w * 2 + (nt >> 1)) * 8 + kt) * 2 + (nt & 1);
        ab[nt] = MFMA16(ah[kt], wbp[fragid * 64 + lane], ab[nt]);
      }
    }
#pragma unroll
    for (int nt = 0; nt < 4; ++nt) {
      const int unit = w * 64 + nt * 16 + col;
      const float bb = b_base[unit];
      const int base_idx =
          (unit >> 5) * 512 + (((unit >> 3) & 3) * 16 + quad * 4) * 8 + (unit & 7);
#pragma unroll
      for (int r2 = 0; r2 < 4; ++r2) {
        const float v = ab[nt][r2] + bb;
        hl2[base_idx + r2 * 8] = (_Float16)fmaxf(v, 0.0f);
      }
    }
  }
  __syncthreads();

  if (w == 0) {
    const half8* __restrict__ wdp = (const half8*)(ws + OFF_WD);
    floatx4 ad = (floatx4){0.f, 0.f, 0.f, 0.f};
#pragma unroll
    for (int kt = 0; kt < 8; ++kt) {
      const half8 ahh = *(const half8*)&hl2[kt * 512 + lane * 8];
      ad = MFMA16(ahh, wdp[kt * 64 + lane], ad);
    }
    const float bd = (col < 8) ? b_dir[col] : b_mag[col - 8];
#pragma unroll
    for (int r2 = 0; r2 < 4; ++r2) {
      const float v = ad[r2] + bd;
      const float act = (col < 8) ? tanh_fast(v) : sigm(v);
      const float other = __shfl_xor(act, 8, 64);
      if (col < 8)
        out[(size_t)(row0 + quad * 4 + r2) * 8 + col] = act * other;
    }
  }
}

// ---------- fallback: R3 single-kernel inline-gi version (correct, slow) ----
#define GRU_BODY(XCUR, XNEXT, TPRE, CUR)                                       \
  {                                                                            \
    __syncthreads();                                                           \
    const _Float16* hc = hlin[CUR];                                            \
    _Float16* hn = hlin[(CUR) ^ 1];                                            \
    half8 st[8];                                                               \
    _Pragma("unroll")                                                          \
    for (int i = 0; i < 8; ++i) st[i] = ghp[(40 + i) * 64 + lane];             \
    {                                                                          \
      const float* p = xlane + (size_t)(TPRE) * 64;                            \
      XNEXT[0] = *(const float4*)(p);                                          \
      XNEXT[1] = *(const float4*)(p + 4);                                      \
      XNEXT[2] = *(const float4*)(p + 32);                                     \
      XNEXT[3] = *(const float4*)(p + 36);                                     \
    }                                                                          \
    half8 ax0, ax1;                                                            \
    ax0[0] = (_Float16)XCUR[0].x; ax0[1] = (_Float16)XCUR[0].y;                \
    ax0[2] = (_Float16)XCUR[0].z; ax0[3] = (_Float16)XCUR[0].w;                \
    ax0[4] = (_Float16)XCUR[1].x; ax0[5] = (_Float16)XCUR[1].y;                \
    ax0[6] = (_Float16)XCUR[1].z; ax0[7] = (_Float16)XCUR[1].w;                \
    ax1[0] = (_Float16)XCUR[2].x; ax1[1] = (_Float16)XCUR[2].y;                \
    ax1[2] = (_Float16)XCUR[2].z; ax1[3] = (_Float16)XCUR[2].w;                \
    ax1[4] = (_Float16)XCUR[3].x; ax1[5] = (_Float16)XCUR[3].y;                \
    ax1[6] = (_Float16)XCUR[3].z; ax1[7] = (_Float16)XCUR[3].w;                \
    half8 ah[8];                                                               \
    _Pragma("unroll")                                                          \
    for (int kt = 0; kt < 8; ++kt)                                             \
      ah[kt] = *(const half8*)&hc[kt * 512 + lane * 8];                        \
    floatx4 acc[8];                                                            \
    _Pragma("unroll")                                                          \
    for (int i = 0; i < 8; ++i) acc[i] = (floatx4){0.f, 0.f, 0.f, 0.f};        \
    _Pragma("unroll")                                                          \
    for (int nt = 0; nt < 6; ++nt) {                                           \
      const int aidx = (nt < 4) ? nt : nt + 2;                                 \
      acc[aidx] = MFMA16(ax0, wg[nt], acc[aidx]);                              \
      acc[aidx] = MFMA16(ax1, wg[6 + nt], acc[aidx]);                          \
    }                                                                          \
    _Pragma("unroll")                                                          \
    for (int f = 0; f < 40; ++f)                                               \
      acc[f % 6] = MFMA16(ah[f / 6], wreg[f], acc[f % 6]);                     \
    _Pragma("unroll")                                                          \
    for (int i = 0; i < 8; ++i) {                                              \
      const int f = 40 + i;                                                    \
      acc[f % 6] = MFMA16(ah[f / 6], st[i], acc[f % 6]);                       \
    }                                                                          \
    _Pragma("unroll")                                                          \
    for (int s = 0; s < 2; ++s) {                                              \
      const int inner = s * 16 + col;                                          \
      const int widx = w * 512 + (inner >> 3) * 128 + (col & 7);               \
      _Pragma("unroll")                                                        \
      for (int r2 = 0; r2 < 4; ++r2) {                                         \
        const float rr = sigm(acc[0 + s][r2] + br[s]);                         \
        const float zz = sigm(acc[2 + s][r2] + bz[s]);                         \
        const float nn = tanh_fast(acc[6 + s][r2] + bin_[s] +                  \
                                   rr * (acc[4 + s][r2] + bhn[s]));            \
        const float hnew = zz * hreg[s][r2] + (1.0f - zz) * nn;                \
        hreg[s][r2] = hnew;                                                    \
        hn[widx + (quad * 4 + r2) * 8] = (_Float16)hnew;                       \
      }                                                                        \
    }                                                                          \
  }

__global__ __launch_bounds__(512, 1)
void gru_all_kernel(const float* __restrict__ x_seq,
                    const float* __restrict__ b_ih,
                    const float* __restrict__ b_hh,
                    const float* __restrict__ b_base,
                    const float* __restrict__ b_dir,
                    const float* __restrict__ b_mag,
                    const _Float16* __restrict__ ws,
                    float* __restrict__ out) {
  __shared__ __align__(16) _Float16 hlin[2][4096];
  const int tid = threadIdx.x;
  const int lane = tid & 63;
  const int w = tid >> 6;
  const int col = lane & 15;
  const int quad = lane >> 4;
  const int row0 = blockIdx.x * 16;

  float br[2], bz[2], bin_[2], bhn[2];
#pragma unroll
  for (int s = 0; s < 2; ++s) {
    const int c = w * 32 + s * 16 + col;
    br[s] = b_ih[c] + b_hh[c];
    bz[s] = b_ih[256 + c] + b_hh[256 + c];
    bin_[s] = b_ih[512 + c];
    bhn[s] = b_hh[512 + c];
  }
  float hreg[2][4];
#pragma unroll
  for (int s = 0; s < 2; ++s)
#pragma unroll
    for (int r2 = 0; r2 < 4; ++r2) hreg[s][r2] = 0.0f;
  *(half8*)&hlin[0][tid * 8] = (half8)((_Float16)0.0f);

  const half8* __restrict__ ghp = (const half8*)(ws + OFF_GH) + w * (48 * 64);
  const half8* __restrict__ gip = (const half8*)(ws + OFF_GI) + w * (12 * 64);
  const half8* __restrict__ wbp = (const half8*)(ws + OFF_WB) + w * (16 * 64);
  const half8* __restrict__ wdp = (const half8*)(ws + OFF_WD);

  half8 wreg[40];
#pragma unroll
  for (int f = 0; f < 40; ++f) wreg[f] = ghp[f * 64 + lane];
  half8 wg[12];
#pragma unroll
  for (int f = 0; f < 12; ++f) wg[f] = gip[f * 64 + lane];

  const float* const xlane =
      x_seq + (size_t)(row0 + col) * (T_SEQ * 64) + quad * 8;
  float4 xc[4], xn[4];
  {
    const float* p = xlane;
    xc[0] = *(const float4*)(p);
    xc[1] = *(const float4*)(p + 4);
    xc[2] = *(const float4*)(p + 32);
    xc[3] = *(const float4*)(p + 36);
  }
#pragma unroll 1
  for (int t = 0; t < T_SEQ; t += 2) {
    GRU_BODY(xc, xn, t + 1, 0);
    const int tp2 = (t + 2 < T_SEQ) ? (t + 2) : (T_SEQ - 1);
    GRU_BODY(xn, xc, tp2, 1);
  }
  __syncthreads();
  {
    floatx4 ab[2];
    ab[0] = (floatx4){0.f, 0.f, 0.f, 0.f};
    ab[1] = (floatx4){0.f, 0.f, 0.f, 0.f};
#pragma unroll
    for (int kt = 0; kt < 8; ++kt) {
      const half8 ahh = *(const half8*)&hlin[0][kt * 512 + lane * 8];
      const half8* bp = wbp + kt * (2 * 64) + lane;
      ab[0] = MFMA16(ahh, bp[0],  ab[0]);
      ab[1] = MFMA16(ahh, bp[64], ab[1]);
    }
#pragma unroll
    for (int s = 0; s < 2; ++s) {
      const int inner = s * 16 + col;
      const int widx = w * 512 + (inner >> 3) * 128 + (col & 7);
      const float bb = b_base[w * 32 + inner];
#pragma unroll
      for (int r2 = 0; r2 < 4; ++r2) {
        const float v = ab[s][r2] + bb;
        hlin[1][widx + (quad * 4 + r2) * 8] = (_Float16)fmaxf(v, 0.0f);
      }
    }
  }
  __syncthreads();
  if (w == 0) {
    floatx4 ad = (floatx4){0.f, 0.f, 0.f, 0.f};
#pragma unroll
    for (int kt = 0; kt < 8; ++kt) {
      const half8 ahh = *(const half8*)&hlin[1][kt * 512 + lane * 8];
      ad = MFMA16(ahh, wdp[kt * 64 + lane], ad);
    }
    const float bd = (col < 8) ? b_dir[col] : b_mag[col - 8];
#pragma unroll
    for (int r2 = 0; r2 < 4; ++r2) {
      const float v = ad[r2] + bd;
      const float act = (col < 8) ? tanh_fast(v) : sigm(v);
      const float other = __shfl_xor(act, 8, 64);
      if (col < 8)
        out[(size_t)(row0 + quad * 4 + r2) * 8 + col] = act * other;
    }
  }
}

extern "C" void kernel_launch(void* const* d_in, const int* in_sizes, int n_in,
                              void* d_out, int out_size, void* d_ws, size_t ws_size,
                              hipStream_t stream) {
  const float* x_seq  = (const float*)d_in[0];
  const float* b_ih   = (const float*)d_in[3];
  const float* b_hh   = (const float*)d_in[4];
  const float* b_base = (const float*)d_in[6];
  const float* b_dir  = (const float*)d_in[8];
  const float* b_mag  = (const float*)d_in[10];
  _Float16* ws = (_Float16*)d_ws;
  float* out = (float*)d_out;

  hipLaunchKernelGGL(prep_kernel, dim3(1097), dim3(64), 0, stream,
                     (const float*)d_in[1], (const float*)d_in[2],
                     (const float*)d_in[5], (const float*)d_in[7],
                     (const float*)d_in[9], ws);

  if (ws_size >= WS_NEED_BYTES) {
    _Float16* x16p = (_Float16*)((char*)d_ws + X16_OFF_BYTES);
    unsigned* seqp = (unsigned*)((char*)d_ws + SEQ_OFF_BYTES);
    unsigned long long* hxp =
        (unsigned long long*)((char*)d_ws + HX_OFF_BYTES);

    hipLaunchKernelGGL(x16_kernel, dim3(2048), dim3(256), 0, stream,
                       x_seq, x16p);

    // PLAIN launch (graph-capture-safe). Co-residency is structural:
    // 256 blocks, launch_bounds(256,1), ~1 block/CU on 256 CUs.
    hipLaunchKernelGGL(gru_coop_kernel, dim3(256), dim3(256), 0, stream,
                       x16p, b_ih, b_hh, b_base, b_dir, b_mag, ws,
                       seqp, hxp, out);
  } else {
    hipLaunchKernelGGL(gru_all_kernel, dim3(64), dim3(512), 0, stream,
                       x_seq, b_ih, b_hh, b_base, b_dir, b_mag, ws, out);
  }
}

// Round 8
// 3692.161 us; speedup vs baseline: 1.2312x; 1.0835x over previous
//
#include <hip/hip_runtime.h>

#define T_SEQ 512
#define HID 256

typedef _Float16 half8 __attribute__((ext_vector_type(8)));
typedef _Float16 half4 __attribute__((ext_vector_type(4)));
typedef float floatx4 __attribute__((ext_vector_type(4)));

// ws layout (f16 element offsets for weight frags):
//   old layout (fallback kernel):  gh | gi | wb | wd
//   split kernel:                  gh2 (per q,w) | gi2 (per q,w)
// byte regions: seqa (padded flags) @2MB, hx_slow @4MB (1MB), x16 @8MB (64MB)
#define OFF_GH 0
#define OFF_GI (OFF_GH + 384 * 512)
#define OFF_WB (OFF_GI + 96 * 512)
#define OFF_WD (OFF_WB + 128 * 512)
#define OFF_GH2 (OFF_WD + 16 * 512)
#define OFF_GI2 (OFF_GH2 + 384 * 512)
#define SEQA_OFF_BYTES (2ull << 20)
#define HXS_OFF_BYTES (4ull << 20)
#define X16_OFF_BYTES (8ull << 20)
#define WS_NEED_BYTES (80ull << 20)

#define MFMA16(A, B, C) __builtin_amdgcn_mfma_f32_16x16x32_f16(A, B, C, 0, 0, 0)

__device__ __forceinline__ float sigm(float x) { return 1.0f / (1.0f + __expf(-x)); }
__device__ __forceinline__ float tanh_fast(float x) {
  float e = __expf(2.0f * x);
  return 1.0f - 2.0f / (e + 1.0f);
}

// Pack all weights (fp32 in) into f16 MFMA B-fragment order (both layouts) +
// zero the (padded) exchange flags. Runs every call => graph-replay-safe reset.
__global__ void prep_kernel(const float* __restrict__ w_ih,
                            const float* __restrict__ w_hh,
                            const float* __restrict__ w_base,
                            const float* __restrict__ w_dir,
                            const float* __restrict__ w_mag,
                            _Float16* __restrict__ ws) {
  const int f = blockIdx.x;
  const int lane = threadIdx.x;
  const int col = lane & 15, quad = lane >> 4;
  const float* src;
  int n, k, ld;
  _Float16* dst;
  if (f < 384) {  // old w_hh frags: f = (w*8 + kt)*6 + nt
    int nt = f % 6, kt = (f / 6) % 8, w = f / 48;
    n = (nt >> 1) * 256 + w * 32 + (nt & 1) * 16 + col;
    k = kt * 32 + quad * 8;
    src = w_hh; ld = 256;
    dst = ws + OFF_GH + ((w * 8 + kt) * 6 + nt) * 512 + lane * 8;
  } else if (f < 480) {  // old w_ih frags
    int f2 = f - 384;
    int nt = f2 % 6, kt = (f2 / 6) % 2, w = f2 / 12;
    n = (nt >> 1) * 256 + w * 32 + (nt & 1) * 16 + col;
    k = kt * 32 + quad * 8;
    src = w_ih; ld = 64;
    dst = ws + OFF_GI + ((w * 2 + kt) * 6 + nt) * 512 + lane * 8;
  } else if (f < 608) {  // w_base frags
    int f3 = f - 480;
    int nt = f3 % 2, kt = (f3 / 2) % 8, w = f3 / 16;
    n = w * 32 + nt * 16 + col;
    k = kt * 32 + quad * 8;
    src = w_base; ld = 256;
    dst = ws + OFF_WB + ((w * 8 + kt) * 2 + nt) * 512 + lane * 8;
  } else if (f < 616) {  // dir/mag combined
    int kt = f - 608;
    k = kt * 32 + quad * 8;
    ld = 256;
    if (col < 8) { src = w_dir; n = col; } else { src = w_mag; n = col - 8; }
    dst = ws + OFF_WD + kt * 512 + lane * 8;
  } else if (f < 1000) {  // gh2 frags: per (qw = q*4+w): [kt(8)][g(3)]
    int f2 = f - 616;
    int g = f2 % 3, kt = (f2 / 3) % 8, qw = f2 / 24;
    n = g * 256 + qw * 16 + col;
    k = kt * 32 + quad * 8;
    src = w_hh; ld = 256;
    dst = ws + OFF_GH2 + ((qw * 8 + kt) * 3 + g) * 512 + lane * 8;
  } else if (f < 1096) {  // gi2 frags: per qw: [kt2(2)][g(3)]
    int f3 = f - 1000;
    int g = f3 % 3, kt = (f3 / 3) % 2, qw = f3 / 6;
    n = g * 256 + qw * 16 + col;
    k = kt * 32 + quad * 8;
    src = w_ih; ld = 64;
    dst = ws + OFF_GI2 + ((qw * 2 + kt) * 3 + g) * 512 + lane * 8;
  } else {  // f == 1096: zero the 256 padded flags (16 dwords apart = 64B)
    unsigned* sa = (unsigned*)((char*)ws + SEQA_OFF_BYTES);
#pragma unroll 1
    for (int i = 0; i < 64; ++i) sa[i * 64 + lane] = 0u;
    return;
  }
#pragma unroll
  for (int j = 0; j < 8; ++j)
    dst[j] = (_Float16)src[n * ld + k + j];
}

// Convert x_seq fp32 -> f16 (same layout) once per call.
__global__ __launch_bounds__(256)
void x16_kernel(const float* __restrict__ x, _Float16* __restrict__ x16) {
  const size_t N8 = (size_t)1024 * 512 * 64 / 8;
  const size_t stride = (size_t)gridDim.x * blockDim.x;
  for (size_t i = (size_t)blockIdx.x * blockDim.x + threadIdx.x; i < N8; i += stride) {
    const float4 a = *(const float4*)(x + i * 8);
    const float4 b = *(const float4*)(x + i * 8 + 4);
    half8 h;
    h[0] = (_Float16)a.x; h[1] = (_Float16)a.y; h[2] = (_Float16)a.z; h[3] = (_Float16)a.w;
    h[4] = (_Float16)b.x; h[5] = (_Float16)b.y; h[6] = (_Float16)b.z; h[7] = (_Float16)b.w;
    *(half8*)(x16 + i * 8) = h;
  }
}

// One exchange-GRU step for block (rg, q), wave w owning 16 hidden units.
// R6-proven LLC protocol (agent atomics for payload + flags) with perf fixes:
// padded flags, s_sleep backoff, single LDS staging of sibling h, own-quarter
// MFMAs before the poll. Parity double-buffer; WAR-safe by flag induction.
#define STEP(AXC, AXN, T)                                                      \
  {                                                                            \
    const int t_ = (T);                                                        \
    floatx4 aR = {0.f, 0.f, 0.f, 0.f}, aZ = {0.f, 0.f, 0.f, 0.f};             \
    floatx4 aNH = {0.f, 0.f, 0.f, 0.f}, aNX = {0.f, 0.f, 0.f, 0.f};           \
    _Pragma("unroll")                                                          \
    for (int k2 = 0; k2 < 2; ++k2) {                                           \
      aR = MFMA16(AXC[k2], wgi[k2 * 3 + 0], aR);                               \
      aZ = MFMA16(AXC[k2], wgi[k2 * 3 + 1], aZ);                               \
      aNX = MFMA16(AXC[k2], wgi[k2 * 3 + 2], aNX);                             \
    }                                                                          \
    {                                                                          \
      const int tn = (t_ + 1 < T_SEQ) ? t_ + 1 : t_;                           \
      AXN[0] = *(const half8*)(xlane16 + (size_t)tn * 64);                     \
      AXN[1] = *(const half8*)(xlane16 + (size_t)tn * 64 + 32);                \
    }                                                                          \
    if (t_ > 0) {                                                              \
      const half8 ao0 = *(const half8*)&hall[(q * 2) * 512 + lane * 8];        \
      const half8 ao1 = *(const half8*)&hall[(q * 2 + 1) * 512 + lane * 8];    \
      aR = MFMA16(ao0, wown[0], aR);                                           \
      aZ = MFMA16(ao0, wown[1], aZ);                                           \
      aNH = MFMA16(ao0, wown[2], aNH);                                         \
      aR = MFMA16(ao1, wown[3], aR);                                           \
      aZ = MFMA16(ao1, wown[4], aZ);                                           \
      aNH = MFMA16(ao1, wown[5], aNH);                                         \
      if (tid < 3) {                                                           \
        const int sq = (q + 1 + tid) & 3;                                      \
        const int fi = (rg4 + sq) * 16;                                        \
        unsigned gd = 0;                                                       \
        while (__hip_atomic_load(seqa + fi, __ATOMIC_ACQUIRE,                  \
                                 __HIP_MEMORY_SCOPE_AGENT) < (unsigned)t_) {   \
          if (++gd > (1u << 20)) break;                                        \
          __builtin_amdgcn_s_sleep(1);                                         \
        }                                                                      \
      }                                                                        \
      __syncthreads();                                                         \
      if (tid < 128) {                                                         \
        const int rh = tid >> 6, l = tid & 63;                                 \
        const size_t pb = (size_t)((t_ & 1) * 64 + rg) * 8;                    \
        const int s0 = (q + 1) & 3, s1 = (q + 2) & 3, s2 = (q + 3) & 3;        \
        const unsigned long long* s0p = hxs + (pb + s0 * 2 + rh) * 128 + l * 2; \
        const unsigned long long* s1p = hxs + (pb + s1 * 2 + rh) * 128 + l * 2; \
        const unsigned long long* s2p = hxs + (pb + s2 * 2 + rh) * 128 + l * 2; \
        union { uint4 u4; unsigned long long u[2]; } v0, v1, v2;               \
        v0.u[0] = __hip_atomic_load(s0p, __ATOMIC_RELAXED, __HIP_MEMORY_SCOPE_AGENT); \
        v0.u[1] = __hip_atomic_load(s0p + 1, __ATOMIC_RELAXED, __HIP_MEMORY_SCOPE_AGENT); \
        v1.u[0] = __hip_atomic_load(s1p, __ATOMIC_RELAXED, __HIP_MEMORY_SCOPE_AGENT); \
        v1.u[1] = __hip_atomic_load(s1p + 1, __ATOMIC_RELAXED, __HIP_MEMORY_SCOPE_AGENT); \
        v2.u[0] = __hip_atomic_load(s2p, __ATOMIC_RELAXED, __HIP_MEMORY_SCOPE_AGENT); \
        v2.u[1] = __hip_atomic_load(s2p + 1, __ATOMIC_RELAXED, __HIP_MEMORY_SCOPE_AGENT); \
        *(uint4*)&hall[(s0 * 2 + rh) * 512 + l * 8] = v0.u4;                   \
        *(uint4*)&hall[(s1 * 2 + rh) * 512 + l * 8] = v1.u4;                   \
        *(uint4*)&hall[(s2 * 2 + rh) * 512 + l * 8] = v2.u4;                   \
      }                                                                        \
      __syncthreads();                                                         \
      _Pragma("unroll")                                                        \
      for (int kt = 0; kt < 8; ++kt) {                                         \
        if ((kt >> 1) != q) { /* uniform branch; own kt already done */        \
          const half8 a = *(const half8*)&hall[kt * 512 + lane * 8];           \
          aR = MFMA16(a, wgh[kt * 3 + 0], aR);                                 \
          aZ = MFMA16(a, wgh[kt * 3 + 1], aZ);                                 \
          aNH = MFMA16(a, wgh[kt * 3 + 2], aNH);                               \
        }                                                                      \
      }                                                                        \
    }                                                                          \
    _Pragma("unroll")                                                          \
    for (int r2 = 0; r2 < 4; ++r2) {                                           \
      const float rr = sigm(aR[r2] + br);                                      \
      const float zz = sigm(aZ[r2] + bz);                                      \
      const float nn = tanh_fast(aNX[r2] + bin_ + rr * (aNH[r2] + bhn));       \
      const float hnew = zz * hreg[r2] + (1.0f - zz) * nn;                     \
      hreg[r2] = hnew;                                                         \
      hall[hallw + r2 * 8] = (_Float16)hnew;                                   \
    }                                                                          \
    __syncthreads();                                                           \
    if (tid < 128) {                                                           \
      const int rh = tid >> 6, l = tid & 63;                                   \
      const int grow = q * 2 + rh;                                             \
      const size_t R = (size_t)(((t_ + 1) & 1) * 64 + rg) * 8 + grow;          \
      union { uint4 u4; unsigned long long u[2]; } v;                          \
      v.u4 = *(const uint4*)&hall[grow * 512 + l * 8];                         \
      unsigned long long* sp = hxs + R * 128 + l * 2;                          \
      __hip_atomic_store(sp, v.u[0], __ATOMIC_RELAXED, __HIP_MEMORY_SCOPE_AGENT); \
      __hip_atomic_store(sp + 1, v.u[1], __ATOMIC_RELAXED, __HIP_MEMORY_SCOPE_AGENT); \
      asm volatile("s_waitcnt vmcnt(0)" ::: "memory");                         \
    }                                                                          \
    __syncthreads();                                                           \
    if (tid == 0)                                                              \
      __hip_atomic_store(&seqa[(rg4 + q) * 16], (unsigned)(t_ + 1),            \
                         __ATOMIC_RELEASE, __HIP_MEMORY_SCOPE_AGENT);          \
  }

// Hidden-split kernel: 256 blocks (rg = bid&63, q = bid>>6) x 256 thr,
// 1 block/CU (1 wave/SIMD => 512-reg budget). All weight frags register-
// resident: zero per-step weight streaming (the ~7300 cyc/step wall of the
// 64-block design). Exchange through the LLC with agent atomics (R6-proven).
__global__ __launch_bounds__(256, 1)
void gru_split_kernel(const _Float16* __restrict__ x16,
                      const float* __restrict__ b_ih,
                      const float* __restrict__ b_hh,
                      const float* __restrict__ b_base,
                      const float* __restrict__ b_dir,
                      const float* __restrict__ b_mag,
                      const _Float16* __restrict__ ws,
                      unsigned* __restrict__ seqa,
                      unsigned long long* __restrict__ hxs,
                      float* __restrict__ out) {
  __shared__ __align__(16) _Float16 hall[4096];  // [kt(8)][512] A-frag rows
  __shared__ __align__(16) _Float16 hl2[4096];   // head: base activations

  const int tid = threadIdx.x;
  const int lane = tid & 63;
  const int w = tid >> 6;
  const int col = lane & 15;
  const int quad = lane >> 4;
  const int rg = blockIdx.x & 63;
  const int q = blockIdx.x >> 6;
  const int rg4 = rg * 4;
  const int row0 = rg * 16;

  const int c = q * 64 + w * 16 + col;
  const float br = b_ih[c] + b_hh[c];
  const float bz = b_ih[256 + c] + b_hh[256 + c];
  const float bin_ = b_ih[512 + c];
  const float bhn = b_hh[512 + c];

  const int qw = q * 4 + w;
  const half8* __restrict__ gh2 = (const half8*)(ws + OFF_GH2) + qw * (24 * 64);
  const half8* __restrict__ gi2 = (const half8*)(ws + OFF_GI2) + qw * (6 * 64);
  half8 wgh[24];
#pragma unroll
  for (int f = 0; f < 24; ++f) wgh[f] = gh2[f * 64 + lane];
  half8 wgi[6];
#pragma unroll
  for (int f = 0; f < 6; ++f) wgi[f] = gi2[f * 64 + lane];
  // own-quarter weight frags in statically-indexed regs (runtime q only in
  // the memory address, never in a register-array index)
  half8 wown[6];
#pragma unroll
  for (int i2 = 0; i2 < 2; ++i2)
#pragma unroll
    for (int g = 0; g < 3; ++g)
      wown[i2 * 3 + g] = gh2[((q * 2 + i2) * 3 + g) * 64 + lane];

  const int ul = w * 16 + col;  // unit_local 0..63 within quarter
  const int hallw =
      q * 1024 + (ul >> 5) * 512 + (((ul >> 3) & 3) * 16 + quad * 4) * 8 + (ul & 7);

  float hreg[4];
#pragma unroll
  for (int r2 = 0; r2 < 4; ++r2) hreg[r2] = 0.0f;

  const _Float16* const xlane16 =
      x16 + (size_t)(row0 + col) * (T_SEQ * 64) + quad * 8;
  half8 axc[2], axn[2];
  axc[0] = *(const half8*)(xlane16);
  axc[1] = *(const half8*)(xlane16 + 32);

#pragma unroll 1
  for (int t = 0; t < T_SEQ; t += 2) {
    STEP(axc, axn, t);
    STEP(axn, axc, t + 1);
  }

  // ---- head (q == 0 blocks; h_512 in parity slot 0) ----
  if (q != 0) return;
  if (tid < 3) {
    const int fi = (rg4 + 1 + tid) * 16;
    unsigned gd = 0;
    while (__hip_atomic_load(seqa + fi, __ATOMIC_ACQUIRE,
                             __HIP_MEMORY_SCOPE_AGENT) < (unsigned)T_SEQ) {
      if (++gd > (1u << 20)) break;
      __builtin_amdgcn_s_sleep(1);
    }
  }
  __syncthreads();
  if (tid < 128) {
    const int rh = tid >> 6, l = tid & 63;
    const size_t pb = (size_t)rg * 8;  // parity 0
    const unsigned long long* s0p = hxs + (pb + 2 + rh) * 128 + l * 2;
    const unsigned long long* s1p = hxs + (pb + 4 + rh) * 128 + l * 2;
    const unsigned long long* s2p = hxs + (pb + 6 + rh) * 128 + l * 2;
    union { uint4 u4; unsigned long long u[2]; } v0, v1, v2;
    v0.u[0] = __hip_atomic_load(s0p, __ATOMIC_RELAXED, __HIP_MEMORY_SCOPE_AGENT);
    v0.u[1] = __hip_atomic_load(s0p + 1, __ATOMIC_RELAXED, __HIP_MEMORY_SCOPE_AGENT);
    v1.u[0] = __hip_atomic_load(s1p, __ATOMIC_RELAXED, __HIP_MEMORY_SCOPE_AGENT);
    v1.u[1] = __hip_atomic_load(s1p + 1, __ATOMIC_RELAXED, __HIP_MEMORY_SCOPE_AGENT);
    v2.u[0] = __hip_atomic_load(s2p, __ATOMIC_RELAXED, __HIP_MEMORY_SCOPE_AGENT);
    v2.u[1] = __hip_atomic_load(s2p + 1, __ATOMIC_RELAXED, __HIP_MEMORY_SCOPE_AGENT);
    *(uint4*)&hall[(2 + rh) * 512 + l * 8] = v0.u4;
    *(uint4*)&hall[(4 + rh) * 512 + l * 8] = v1.u4;
    *(uint4*)&hall[(6 + rh) * 512 + l * 8] = v2.u4;
  }
  __syncthreads();

  // base = relu(h @ w_base^T + b_base); wave w owns units [w*64, w*64+64)
  {
    const half8* __restrict__ wbp = (const half8*)(ws + OFF_WB);
    floatx4 ab[4];
#pragma unroll
    for (int nt = 0; nt < 4; ++nt) ab[nt] = (floatx4){0.f, 0.f, 0.f, 0.f};
#pragma unroll
    for (int kt = 0; kt < 8; ++kt) {
      const half8 ahh = *(const half8*)&hall[kt * 512 + lane * 8];
#pragma unroll
      for (int nt = 0; nt < 4; ++nt) {
        const int fragid = ((w * 2 + (nt >> 1)) * 8 + kt) * 2 + (nt & 1);
        ab[nt] = MFMA16(ahh, wbp[fragid * 64 + lane], ab[nt]);
      }
    }
#pragma unroll
    for (int nt = 0; nt < 4; ++nt) {
      const int unit = w * 64 + nt * 16 + col;
      const float bb = b_base[unit];
      const int base_idx =
          (unit >> 5) * 512 + (((unit >> 3) & 3) * 16 + quad * 4) * 8 + (unit & 7);
#pragma unroll
      for (int r2 = 0; r2 < 4; ++r2) {
        const float v = ab[nt][r2] + bb;
        hl2[base_idx + r2 * 8] = (_Float16)fmaxf(v, 0.0f);
      }
    }
  }
  __syncthreads();

  if (w == 0) {
    const half8* __restrict__ wdp = (const half8*)(ws + OFF_WD);
    floatx4 ad = (floatx4){0.f, 0.f, 0.f, 0.f};
#pragma unroll
    for (int kt = 0; kt < 8; ++kt) {
      const half8 ahh = *(const half8*)&hl2[kt * 512 + lane * 8];
      ad = MFMA16(ahh, wdp[kt * 64 + lane], ad);
    }
    const float bd = (col < 8) ? b_dir[col] : b_mag[col - 8];
#pragma unroll
    for (int r2 = 0; r2 < 4; ++r2) {
      const float v = ad[r2] + bd;
      const float act = (col < 8) ? tanh_fast(v) : sigm(v);
      const float other = __shfl_xor(act, 8, 64);
      if (col < 8)
        out[(size_t)(row0 + quad * 4 + r2) * 8 + col] = act * other;
    }
  }
}

// ---------- fallback: R3 single-kernel inline-gi version (correct, slow) ----
#define GRU_BODY(XCUR, XNEXT, TPRE, CUR)                                       \
  {                                                                            \
    __syncthreads();                                                           \
    const _Float16* hc = hlin[CUR];                                            \
    _Float16* hn = hlin[(CUR) ^ 1];                                            \
    half8 st[8];                                                               \
    _Pragma("unroll")                                                          \
    for (int i = 0; i < 8; ++i) st[i] = ghp[(40 + i) * 64 + lane];             \
    {                                                                          \
      const float* p = xlane + (size_t)(TPRE) * 64;                            \
      XNEXT[0] = *(const float4*)(p);                                          \
      XNEXT[1] = *(const float4*)(p + 4);                                      \
      XNEXT[2] = *(const float4*)(p + 32);                                     \
      XNEXT[3] = *(const float4*)(p + 36);                                     \
    }                                                                          \
    half8 ax0, ax1;                                                            \
    ax0[0] = (_Float16)XCUR[0].x; ax0[1] = (_Float16)XCUR[0].y;                \
    ax0[2] = (_Float16)XCUR[0].z; ax0[3] = (_Float16)XCUR[0].w;                \
    ax0[4] = (_Float16)XCUR[1].x; ax0[5] = (_Float16)XCUR[1].y;                \
    ax0[6] = (_Float16)XCUR[1].z; ax0[7] = (_Float16)XCUR[1].w;                \
    ax1[0] = (_Float16)XCUR[2].x; ax1[1] = (_Float16)XCUR[2].y;                \
    ax1[2] = (_Float16)XCUR[2].z; ax1[3] = (_Float16)XCUR[2].w;                \
    ax1[4] = (_Float16)XCUR[3].x; ax1[5] = (_Float16)XCUR[3].y;                \
    ax1[6] = (_Float16)XCUR[3].z; ax1[7] = (_Float16)XCUR[3].w;                \
    half8 ah[8];                                                               \
    _Pragma("unroll")                                                          \
    for (int kt = 0; kt < 8; ++kt)                                             \
      ah[kt] = *(const half8*)&hc[kt * 512 + lane * 8];                        \
    floatx4 acc[8];                                                            \
    _Pragma("unroll")                                                          \
    for (int i = 0; i < 8; ++i) acc[i] = (floatx4){0.f, 0.f, 0.f, 0.f};        \
    _Pragma("unroll")                                                          \
    for (int nt = 0; nt < 6; ++nt) {                                           \
      const int aidx = (nt < 4) ? nt : nt + 2;                                 \
      acc[aidx] = MFMA16(ax0, wg[nt], acc[aidx]);                              \
      acc[aidx] = MFMA16(ax1, wg[6 + nt], acc[aidx]);                          \
    }                                                                          \
    _Pragma("unroll")                                                          \
    for (int f = 0; f < 40; ++f)                                               \
      acc[f % 6] = MFMA16(ah[f / 6], wreg[f], acc[f % 6]);                     \
    _Pragma("unroll")                                                          \
    for (int i = 0; i < 8; ++i) {                                              \
      const int f = 40 + i;                                                    \
      acc[f % 6] = MFMA16(ah[f / 6], st[i], acc[f % 6]);                       \
    }                                                                          \
    _Pragma("unroll")                                                          \
    for (int s = 0; s < 2; ++s) {                                              \
      const int inner = s * 16 + col;                                          \
      const int widx = w * 512 + (inner >> 3) * 128 + (col & 7);               \
      _Pragma("unroll")                                                        \
      for (int r2 = 0; r2 < 4; ++r2) {                                         \
        const float rr = sigm(acc[0 + s][r2] + br[s]);                         \
        const float zz = sigm(acc[2 + s][r2] + bz[s]);                         \
        const float nn = tanh_fast(acc[6 + s][r2] + bin_[s] +                  \
                                   rr * (acc[4 + s][r2] + bhn[s]));            \
        const float hnew = zz * hreg[s][r2] + (1.0f - zz) * nn;                \
        hreg[s][r2] = hnew;                                                    \
        hn[widx + (quad * 4 + r2) * 8] = (_Float16)hnew;                       \
      }                                                                        \
    }                                                                          \
  }

__global__ __launch_bounds__(512, 1)
void gru_all_kernel(const float* __restrict__ x_seq,
                    const float* __restrict__ b_ih,
                    const float* __restrict__ b_hh,
                    const float* __restrict__ b_base,
                    const float* __restrict__ b_dir,
                    const float* __restrict__ b_mag,
                    const _Float16* __restrict__ ws,
                    float* __restrict__ out) {
  __shared__ __align__(16) _Float16 hlin[2][4096];
  const int tid = threadIdx.x;
  const int lane = tid & 63;
  const int w = tid >> 6;
  const int col = lane & 15;
  const int quad = lane >> 4;
  const int row0 = blockIdx.x * 16;

  float br[2], bz[2], bin_[2], bhn[2];
#pragma unroll
  for (int s = 0; s < 2; ++s) {
    const int c = w * 32 + s * 16 + col;
    br[s] = b_ih[c] + b_hh[c];
    bz[s] = b_ih[256 + c] + b_hh[256 + c];
    bin_[s] = b_ih[512 + c];
    bhn[s] = b_hh[512 + c];
  }
  float hreg[2][4];
#pragma unroll
  for (int s = 0; s < 2; ++s)
#pragma unroll
    for (int r2 = 0; r2 < 4; ++r2) hreg[s][r2] = 0.0f;
  *(half8*)&hlin[0][tid * 8] = (half8)((_Float16)0.0f);

  const half8* __restrict__ ghp = (const half8*)(ws + OFF_GH) + w * (48 * 64);
  const half8* __restrict__ gip = (const half8*)(ws + OFF_GI) + w * (12 * 64);
  const half8* __restrict__ wbp = (const half8*)(ws + OFF_WB) + w * (16 * 64);
  const half8* __restrict__ wdp = (const half8*)(ws + OFF_WD);

  half8 wreg[40];
#pragma unroll
  for (int f = 0; f < 40; ++f) wreg[f] = ghp[f * 64 + lane];
  half8 wg[12];
#pragma unroll
  for (int f = 0; f < 12; ++f) wg[f] = gip[f * 64 + lane];

  const float* const xlane =
      x_seq + (size_t)(row0 + col) * (T_SEQ * 64) + quad * 8;
  float4 xc[4], xn[4];
  {
    const float* p = xlane;
    xc[0] = *(const float4*)(p);
    xc[1] = *(const float4*)(p + 4);
    xc[2] = *(const float4*)(p + 32);
    xc[3] = *(const float4*)(p + 36);
  }
#pragma unroll 1
  for (int t = 0; t < T_SEQ; t += 2) {
    GRU_BODY(xc, xn, t + 1, 0);
    const int tp2 = (t + 2 < T_SEQ) ? (t + 2) : (T_SEQ - 1);
    GRU_BODY(xn, xc, tp2, 1);
  }
  __syncthreads();
  {
    floatx4 ab[2];
    ab[0] = (floatx4){0.f, 0.f, 0.f, 0.f};
    ab[1] = (floatx4){0.f, 0.f, 0.f, 0.f};
#pragma unroll
    for (int kt = 0; kt < 8; ++kt) {
      const half8 ahh = *(const half8*)&hlin[0][kt * 512 + lane * 8];
      const half8* bp = wbp + kt * (2 * 64) + lane;
      ab[0] = MFMA16(ahh, bp[0],  ab[0]);
      ab[1] = MFMA16(ahh, bp[64], ab[1]);
    }
#pragma unroll
    for (int s = 0; s < 2; ++s) {
      const int inner = s * 16 + col;
      const int widx = w * 512 + (inner >> 3) * 128 + (col & 7);
      const float bb = b_base[w * 32 + inner];
#pragma unroll
      for (int r2 = 0; r2 < 4; ++r2) {
        const float v = ab[s][r2] + bb;
        hlin[1][widx + (quad * 4 + r2) * 8] = (_Float16)fmaxf(v, 0.0f);
      }
    }
  }
  __syncthreads();
  if (w == 0) {
    floatx4 ad = (floatx4){0.f, 0.f, 0.f, 0.f};
#pragma unroll
    for (int kt = 0; kt < 8; ++kt) {
      const half8 ahh = *(const half8*)&hlin[1][kt * 512 + lane * 8];
      ad = MFMA16(ahh, wdp[kt * 64 + lane], ad);
    }
    const float bd = (col < 8) ? b_dir[col] : b_mag[col - 8];
#pragma unroll
    for (int r2 = 0; r2 < 4; ++r2) {
      const float v = ad[r2] + bd;
      const float act = (col < 8) ? tanh_fast(v) : sigm(v);
      const float other = __shfl_xor(act, 8, 64);
      if (col < 8)
        out[(size_t)(row0 + quad * 4 + r2) * 8 + col] = act * other;
    }
  }
}

extern "C" void kernel_launch(void* const* d_in, const int* in_sizes, int n_in,
                              void* d_out, int out_size, void* d_ws, size_t ws_size,
                              hipStream_t stream) {
  const float* x_seq  = (const float*)d_in[0];
  const float* b_ih   = (const float*)d_in[3];
  const float* b_hh   = (const float*)d_in[4];
  const float* b_base = (const float*)d_in[6];
  const float* b_dir  = (const float*)d_in[8];
  const float* b_mag  = (const float*)d_in[10];
  _Float16* ws = (_Float16*)d_ws;
  float* out = (float*)d_out;

  hipLaunchKernelGGL(prep_kernel, dim3(1097), dim3(64), 0, stream,
                     (const float*)d_in[1], (const float*)d_in[2],
                     (const float*)d_in[5], (const float*)d_in[7],
                     (const float*)d_in[9], ws);

  if (ws_size >= WS_NEED_BYTES) {
    _Float16* x16p = (_Float16*)((char*)d_ws + X16_OFF_BYTES);
    unsigned* seqa = (unsigned*)((char*)d_ws + SEQA_OFF_BYTES);
    unsigned long long* hxs =
        (unsigned long long*)((char*)d_ws + HXS_OFF_BYTES);

    hipLaunchKernelGGL(x16_kernel, dim3(2048), dim3(256), 0, stream,
                       x_seq, x16p);

    hipLaunchKernelGGL(gru_split_kernel, dim3(256), dim3(256), 0, stream,
                       x16p, b_ih, b_hh, b_base, b_dir, b_mag, ws,
                       seqa, hxs, out);
  } else {
    hipLaunchKernelGGL(gru_all_kernel, dim3(64), dim3(512), 0, stream,
                       x_seq, b_ih, b_hh, b_base, b_dir, b_mag, ws, out);
  }
}